// Round 4
// baseline (457.387 us; speedup 1.0000x reference)
//
#include <hip/hip_runtime.h>
#include <hip/hip_bf16.h>

#define TOKENS 2048
#define DIM    1024
#define FDIM   1408
#define NEXP   16
#define NK     (TOKENS * 2)
#define CAP    320
#define RPAD   384          // padded rows per expert (3 x 128)

typedef __attribute__((ext_vector_type(4))) float f32x4;
typedef __attribute__((ext_vector_type(8))) short s16x8;
typedef __attribute__((ext_vector_type(4))) short s16x4;

__device__ __forceinline__ short f2bf(float f) {
    unsigned int u = __float_as_uint(f);
    u += 0x7FFFu + ((u >> 16) & 1u);   // RNE
    return (short)(u >> 16);
}
__device__ __forceinline__ float bf2f(short s) {
    return __uint_as_float(((unsigned int)(unsigned short)s) << 16);
}

#define GLDS16(gp, lp) __builtin_amdgcn_global_load_lds(                     \
    (const __attribute__((address_space(1))) unsigned int*)(gp),             \
    (__attribute__((address_space(3))) unsigned int*)(lp), 16, 0, 0)

// ---------------- arg structs ----------------
struct GSeg {
    const short* A; long aStride; int aRpad;
    const short* B0; const short* B1; long bStride;
    short* Out; long oStride; int oRpad;
    const int* cnt; int Mb, Nb, N, K, nblocks;
};
struct WSeg { const float* in; short* out; int K, N, mats, nblocks; };

// ------- Weight chunk-reorder device: fp32 [K][N] -> bf16 [K/8][N][8] -------
// block = 128 n-cols x 16 k-slabs; 256 threads, 8 units each
__device__ void wchunk_dev(const WSeg& W, int bid)
{
    const int pm  = W.nblocks / W.mats;
    const int mat = bid / pm, r = bid % pm;
    const int nbl = W.N >> 7;
    const int nb  = r % nbl, kb = r / nbl;
    const int t   = threadIdx.x;
    const int n   = nb * 128 + (t & 127);
    const int s0  = kb * 16 + (t >> 7);
    const float* in = W.in + (size_t)mat * W.K * W.N;
    short* out = W.out + (size_t)mat * W.K * W.N;
#pragma unroll
    for (int i = 0; i < 8; i++) {
        int s = s0 + i * 2;
        const float* src = in + (size_t)s * 8 * W.N + n;
        s16x8 o;
#pragma unroll
        for (int j = 0; j < 8; j++) o[j] = f2bf(src[(size_t)j * W.N]);
        *(s16x8*)(out + (size_t)s * W.N * 8 + (size_t)n * 8) = o;
    }
}

// -------- Router device: logits -> softmax -> top2 -> renormalize -----------
__device__ void router_dev(const float* __restrict__ x, const float* __restrict__ rw,
                           const float* __restrict__ rb, int* __restrict__ idx_flat,
                           float* __restrict__ vals_flat, int bid)
{
    __shared__ float lg[16][17];
    const int t  = threadIdx.x;
    const int tl = t >> 4;
    const int e  = t & 15;
    const int token = bid * 16 + tl;
    const float* xr = x + (size_t)token * DIM;

    float acc = 0.f;
    for (int d4 = 0; d4 < DIM / 4; d4++) {
        float4 xv = *(const float4*)(xr + d4 * 4);
        acc += xv.x * rw[(d4 * 4 + 0) * NEXP + e];
        acc += xv.y * rw[(d4 * 4 + 1) * NEXP + e];
        acc += xv.z * rw[(d4 * 4 + 2) * NEXP + e];
        acc += xv.w * rw[(d4 * 4 + 3) * NEXP + e];
    }
    lg[tl][e] = acc + rb[e];
    __syncthreads();

    if (t < 16) {
        float l[16];
#pragma unroll
        for (int j = 0; j < 16; j++) l[j] = lg[t][j];
        float m = l[0];
#pragma unroll
        for (int j = 1; j < 16; j++) m = fmaxf(m, l[j]);
        float p[16], den = 0.f;
#pragma unroll
        for (int j = 0; j < 16; j++) { p[j] = __expf(l[j] - m); den += p[j]; }
        int i1 = -1; float b1 = -1e30f;
#pragma unroll
        for (int j = 0; j < 16; j++) if (p[j] > b1) { b1 = p[j]; i1 = j; }
        int i2 = -1; float b2 = -1e30f;
#pragma unroll
        for (int j = 0; j < 16; j++) if (j != i1 && p[j] > b2) { b2 = p[j]; i2 = j; }
        float v1 = b1 / den, v2 = b2 / den;
        float s = v1 + v2 + 1e-9f;
        int tok = bid * 16 + t;
        idx_flat[tok * 2 + 0] = i1;
        idx_flat[tok * 2 + 1] = i2;
        vals_flat[tok * 2 + 0] = v1 / s;
        vals_flat[tok * 2 + 1] = v2 / s;
    }
}

// -------- xconv device: x -> bf16 chunk [DIM/8][TOKENS][8]; 2 tokens/block --
__device__ void xconv_dev(const float* __restrict__ x, short* __restrict__ xb, int bid)
{
    const int token = bid * 2 + (threadIdx.x >> 7);
    const int c = threadIdx.x & 127;
    const float* src = x + (size_t)token * DIM + c * 8;
    float4 v0 = *(const float4*)(src);
    float4 v1 = *(const float4*)(src + 4);
    s16x8 o;
    o[0] = f2bf(v0.x); o[1] = f2bf(v0.y); o[2] = f2bf(v0.z); o[3] = f2bf(v0.w);
    o[4] = f2bf(v1.x); o[5] = f2bf(v1.y); o[6] = f2bf(v1.z); o[7] = f2bf(v1.w);
    *(s16x8*)(xb + (size_t)c * (TOKENS * 8) + (size_t)token * 8) = o;
}

// ---------------- K1: weight(g/u) conversion + router + xconv ---------------
__global__ __launch_bounds__(256) void prep_kernel(
    WSeg w0, WSeg w1, WSeg w2, WSeg w3,
    const float* __restrict__ x, const float* __restrict__ rw,
    const float* __restrict__ rb, int* __restrict__ idx_flat,
    float* __restrict__ vals, short* __restrict__ xb)
{
    int bid = blockIdx.x;
    if (bid < w0.nblocks) { wchunk_dev(w0, bid); return; }
    bid -= w0.nblocks;
    if (bid < w1.nblocks) { wchunk_dev(w1, bid); return; }
    bid -= w1.nblocks;
    if (bid < w2.nblocks) { wchunk_dev(w2, bid); return; }
    bid -= w2.nblocks;
    if (bid < w3.nblocks) { wchunk_dev(w3, bid); return; }
    bid -= w3.nblocks;
    if (bid < TOKENS / 16) { router_dev(x, rw, rb, idx_flat, vals, bid); return; }
    bid -= TOKENS / 16;
    xconv_dev(x, xb, bid);
}

// ------------- Sequential position scan (1 wave, ballot-based) --------------
__global__ void scan_kernel(const int* __restrict__ idx_flat,
                            const float* __restrict__ vals,
                            int* __restrict__ dst, float* __restrict__ wgt,
                            int* __restrict__ cnt)
{
    const int lane = threadIdx.x;   // 64 threads
    int base[16];
#pragma unroll
    for (int e = 0; e < 16; e++) base[e] = 0;

    for (int c = 0; c < NK / 64; c++) {
        int i = c * 64 + lane;
        int e = idx_flat[i];
        unsigned long long m[16];
#pragma unroll
        for (int ee = 0; ee < 16; ee++) m[ee] = __ballot(e == ee);
        unsigned long long mym = 0ULL; int myb = 0;
#pragma unroll
        for (int ee = 0; ee < 16; ee++) {
            bool sel = (e == ee);
            mym = sel ? m[ee] : mym;
            myb = sel ? base[ee] : myb;
        }
        int pos = myb + (int)__popcll(mym & ((1ULL << lane) - 1ULL));
        bool within = pos < CAP;
        dst[i] = within ? (e * RPAD + pos) : -1;
        wgt[i] = within ? vals[i] : 0.f;
#pragma unroll
        for (int ee = 0; ee < 16; ee++) base[ee] += (int)__popcll(m[ee]);
    }
    if (lane < 16) cnt[lane] = base[lane] < CAP ? base[lane] : CAP;
}

// ---- Scatter token into expert buffer, chunk layout [K/8][RPAD][8] ---------
// 2 entries per block (256 threads)
__global__ __launch_bounds__(256) void scatter_kernel(
    const float* __restrict__ x, const int* __restrict__ dst,
    const int* __restrict__ idx_flat, short* __restrict__ ex)
{
    const int i = blockIdx.x * 2 + (threadIdx.x >> 7);
    const int d0 = dst[i];
    if (d0 < 0) return;
    const int e = idx_flat[i];
    const int pos = d0 - e * RPAD;
    const int token = i >> 1;
    const int c = threadIdx.x & 127;
    const float* src = x + (size_t)token * DIM + c * 8;
    float4 v0 = *(const float4*)(src);
    float4 v1 = *(const float4*)(src + 4);
    s16x8 o;
    o[0] = f2bf(v0.x); o[1] = f2bf(v0.y); o[2] = f2bf(v0.z); o[3] = f2bf(v0.w);
    o[4] = f2bf(v1.x); o[5] = f2bf(v1.y); o[6] = f2bf(v1.z); o[7] = f2bf(v1.w);
    *(s16x8*)(ex + (size_t)e * (DIM * RPAD) + (size_t)c * (RPAD * 8) +
              (size_t)pos * 8) = o;
}

// ---------------- Grouped GEMM device, depth-2 counted-vmcnt pipeline -------
// A: chunk [K/8][aRpad][8] bf16; B: chunk [K/8][N][8] bf16.
// NMAT=2: Out = silu(A@B0)*(A@B1) stored chunk [N/8][oRpad][8]
// NMAT=1: Out = A@B0 stored canonical [row][N]
// Tile 128x128(xNMAT), BK=32, 4 waves (2x2), each 64x64 per mat.
template <int NMAT>
__device__ void gemm_dev(const GSeg& S, int bid)
{
    constexpr int BUFS = 4096 * (1 + NMAT);     // shorts per pipeline buffer
    __shared__ short lds[2 * BUFS];

    // XCD-aware swizzle (segment nblocks % 8 == 0), m fastest
    const int cpx = S.nblocks >> 3;
    const int lid = (bid & 7) * cpx + (bid >> 3);
    const int mb  = lid % S.Mb;
    const int t1  = lid / S.Mb;
    const int nb  = t1 % S.Nb;
    const int g   = t1 / S.Nb;
    const int m0 = mb * 128, n0 = nb * 128;
    if (S.cnt != nullptr && m0 >= S.cnt[g]) return;

    const int tid = threadIdx.x, lane = tid & 63, w = tid >> 6;
    const int wr = w >> 1, wc = w & 1, ln = lane & 15, kg = lane >> 4;

    const int N = S.N, K = S.K;
    const short* Ag  = S.A  + (size_t)g * S.aStride + (size_t)m0 * 8;
    const short* Bg0 = S.B0 + (size_t)g * S.bStride + (size_t)n0 * 8;
    const short* Bg1 = nullptr;
    if constexpr (NMAT == 2) Bg1 = S.B1 + (size_t)g * S.bStride + (size_t)n0 * 8;

    const size_t aR8 = (size_t)S.aRpad * 8;   // shorts per A k-slab
    const size_t n8  = (size_t)N * 8;         // shorts per B k-slab

    const int srow = tid & 127, sslab = tid >> 7;
    const short* aS0 = Ag  + sslab * aR8 + srow * 8;
    const short* aS1 = Ag  + (2 + sslab) * aR8 + srow * 8;
    const short* bS00 = Bg0 + sslab * n8 + srow * 8;
    const short* bS01 = Bg0 + (2 + sslab) * n8 + srow * 8;
    const short* bS10 = nullptr, *bS11 = nullptr;
    if constexpr (NMAT == 2) {
        bS10 = Bg1 + sslab * n8 + srow * 8;
        bS11 = Bg1 + (2 + sslab) * n8 + srow * 8;
    }

    // wave-uniform LDS dest offsets (shorts): HW adds lane*16B
    const int dA0 = w * 512, dA1 = 2048 + w * 512;

    auto STG = [&](int buf, int ks) {
        const size_t ka = (size_t)ks * 4 * aR8;
        const size_t kb = (size_t)ks * 4 * n8;
        short* base = lds + buf * BUFS;
        GLDS16(aS0 + ka,  base + dA0);
        GLDS16(aS1 + ka,  base + dA1);
        GLDS16(bS00 + kb, base + 4096 + dA0);
        GLDS16(bS01 + kb, base + 4096 + dA1);
        if constexpr (NMAT == 2) {
            GLDS16(bS10 + kb, base + 8192 + dA0);
            GLDS16(bS11 + kb, base + 8192 + dA1);
        }
    };

    // frag read offsets (shorts): LDS per buf = [4 kg][128 row][8]
    const int aO = kg * 1024 + (wr * 64 + ln) * 8;
    const int bO = kg * 1024 + (wc * 64 + ln) * 8;

    f32x4 acc[NMAT][4][4] = {};

    const int nt = K / 32;
    STG(0, 0); STG(1, 1);
    int cur = 0;
    for (int ks = 0; ks < nt; ks++) {
        if (ks + 1 < nt) {
            if constexpr (NMAT == 2) asm volatile("s_waitcnt vmcnt(6)" ::: "memory");
            else                     asm volatile("s_waitcnt vmcnt(4)" ::: "memory");
        } else {
            asm volatile("s_waitcnt vmcnt(0)" ::: "memory");
        }
        __builtin_amdgcn_s_barrier();
        __builtin_amdgcn_sched_barrier(0);

        const short* base = lds + cur * BUFS;
        s16x8 af[4];
#pragma unroll
        for (int m = 0; m < 4; m++)
            af[m] = *(const s16x8*)(base + aO + m * 128);
        s16x8 bf[NMAT][4];
#pragma unroll
        for (int mat = 0; mat < NMAT; mat++)
#pragma unroll
            for (int nf = 0; nf < 4; nf++)
                bf[mat][nf] = *(const s16x8*)(base + 4096 + mat * 4096 + bO + nf * 128);

        __builtin_amdgcn_s_setprio(1);
#pragma unroll
        for (int nf = 0; nf < 4; nf++)
#pragma unroll
            for (int m = 0; m < 4; m++)
#pragma unroll
                for (int mat = 0; mat < NMAT; mat++)
                    acc[mat][m][nf] = __builtin_amdgcn_mfma_f32_16x16x32_bf16(
                        af[m], bf[mat][nf], acc[mat][m][nf], 0, 0, 0);
        __builtin_amdgcn_s_setprio(0);
        __builtin_amdgcn_sched_barrier(0);
        __builtin_amdgcn_s_barrier();

        if (ks + 2 < nt) STG(cur, ks + 2);
        cur ^= 1;
    }

    // Epilogue. C/D: col = lane&15, row = (lane>>4)*4 + j  [m89-verified]
#pragma unroll
    for (int m = 0; m < 4; m++) {
#pragma unroll
        for (int nf = 0; nf < 4; nf++) {
            const int row = m0 + wr * 64 + m * 16 + kg * 4;
            const int col = n0 + wc * 64 + nf * 16 + ln;
#pragma unroll
            for (int j = 0; j < 4; j++) {
                if constexpr (NMAT == 2) {
                    float gv = acc[0][m][nf][j];
                    float uv = acc[1][m][nf][j];
                    float v = gv / (1.f + __expf(-gv)) * uv;
                    S.Out[(size_t)g * S.oStride + (size_t)(col >> 3) * (S.oRpad * 8) +
                          (size_t)(row + j) * 8 + (col & 7)] = f2bf(v);
                } else {
                    S.Out[(size_t)g * S.oStride + (size_t)(row + j) * N + col] =
                        f2bf(acc[0][m][nf][j]);
                }
            }
        }
    }
}

// ---------------- K2: gate+up GEMMs + down-weight conversion ----------------
__global__ __launch_bounds__(256, 3) void gateup_kernel(GSeg s0, GSeg s1,
                                                        WSeg w0, WSeg w1)
{
    int bid = blockIdx.x;
    if (bid < s0.nblocks) { gemm_dev<2>(s0, bid); return; }
    bid -= s0.nblocks;
    if (bid < s1.nblocks) { gemm_dev<2>(s1, bid); return; }
    bid -= s1.nblocks;
    if (bid < w0.nblocks) { wchunk_dev(w0, bid); return; }
    bid -= w0.nblocks;
    wchunk_dev(w1, bid);
}

// ---------------- K3: down GEMMs --------------------------------------------
__global__ __launch_bounds__(256, 4) void down_kernel(GSeg s0, GSeg s1)
{
    int bid = blockIdx.x;
    if (bid < s0.nblocks) { gemm_dev<1>(s0, bid); return; }
    bid -= s0.nblocks;
    gemm_dev<1>(s1, bid);
}

// ---------------- Combine: out = x + shared + sum_k w_k * expert_row --------
__global__ __launch_bounds__(256) void combine_kernel(
    const float* __restrict__ x, const short* __restrict__ shout,
    const short* __restrict__ eout, const int* __restrict__ dst,
    const float* __restrict__ wgt, float* __restrict__ out)
{
    const int t = blockIdx.x;
    const int d = threadIdx.x * 4;
    size_t o = (size_t)t * DIM + d;
    float4 xv = *(const float4*)(x + o);
    s16x4 sv = *(const s16x4*)(shout + o);
    float r0 = xv.x + bf2f(sv[0]);
    float r1 = xv.y + bf2f(sv[1]);
    float r2 = xv.z + bf2f(sv[2]);
    float r3 = xv.w + bf2f(sv[3]);
#pragma unroll
    for (int k = 0; k < 2; k++) {
        int di = dst[t * 2 + k];
        if (di >= 0) {
            float wv = wgt[t * 2 + k];
            s16x4 ev = *(const s16x4*)(eout + (size_t)di * DIM + d);
            r0 += wv * bf2f(ev[0]);
            r1 += wv * bf2f(ev[1]);
            r2 += wv * bf2f(ev[2]);
            r3 += wv * bf2f(ev[3]);
        }
    }
    float4 rv = {r0, r1, r2, r3};
    *(float4*)(out + o) = rv;
}

extern "C" void kernel_launch(void* const* d_in, const int* in_sizes, int n_in,
                              void* d_out, int out_size, void* d_ws, size_t ws_size,
                              hipStream_t stream)
{
    const float* x   = (const float*)d_in[0];
    const float* rw  = (const float*)d_in[1];
    const float* rb  = (const float*)d_in[2];
    const float* wg  = (const float*)d_in[3];
    const float* wu  = (const float*)d_in[4];
    const float* wd  = (const float*)d_in[5];
    const float* swg = (const float*)d_in[6];
    const float* swu = (const float*)d_in[7];
    const float* swd = (const float*)d_in[8];
    float* out = (float*)d_out;

    char* wp = (char*)d_ws;
    auto alloc = [&](size_t b) { char* p = wp; wp += (b + 255) & ~(size_t)255; return p; };
    int*   idx_flat = (int*)alloc((size_t)NK * 4);
    float* vals     = (float*)alloc((size_t)NK * 4);
    int*   dst      = (int*)alloc((size_t)NK * 4);
    float* wgt      = (float*)alloc((size_t)NK * 4);
    int*   cnt      = (int*)alloc(64);
    short* xb       = (short*)alloc((size_t)TOKENS * DIM * 2);          // chunk
    short* ex       = (short*)alloc((size_t)NEXP * RPAD * DIM * 2);     // chunk
    short* acte     = (short*)alloc((size_t)NEXP * RPAD * FDIM * 2);    // chunk
    short* acts     = (short*)alloc((size_t)TOKENS * FDIM * 2);         // chunk
    short* eout     = (short*)alloc((size_t)NEXP * RPAD * DIM * 2);     // canonical
    short* shout    = (short*)alloc((size_t)TOKENS * DIM * 2);          // canonical
    short* wgC      = (short*)alloc((size_t)NEXP * DIM * FDIM * 2);
    short* wuC      = (short*)alloc((size_t)NEXP * DIM * FDIM * 2);
    short* wdC      = (short*)alloc((size_t)NEXP * DIM * FDIM * 2);
    short* swgC     = (short*)alloc((size_t)DIM * FDIM * 2);
    short* swuC     = (short*)alloc((size_t)DIM * FDIM * 2);
    short* swdC     = (short*)alloc((size_t)DIM * FDIM * 2);

    // WSeg: blocks/mat = (N/128)*(K/128)
    WSeg Wg  = {wg,  wgC,  DIM,  FDIM, NEXP, 11 * 8 * NEXP};   // 1408
    WSeg Wu  = {wu,  wuC,  DIM,  FDIM, NEXP, 11 * 8 * NEXP};   // 1408
    WSeg Wsg = {swg, swgC, DIM,  FDIM, 1,    11 * 8};          // 88
    WSeg Wsu = {swu, swuC, DIM,  FDIM, 1,    11 * 8};          // 88
    WSeg Wd  = {wd,  wdC,  FDIM, DIM,  NEXP, 8 * 11 * NEXP};   // 1408
    WSeg Wsd = {swd, swdC, FDIM, DIM,  1,    8 * 11};          // 88

    // K1: g/u weight conversion + router + xconv
    const int prep_blocks = Wg.nblocks + Wu.nblocks + Wsg.nblocks + Wsu.nblocks
                          + TOKENS / 16 + TOKENS / 2;
    prep_kernel<<<prep_blocks, 256, 0, stream>>>(Wg, Wu, Wsg, Wsu,
                                                 x, rw, rb, idx_flat, vals, xb);
    scan_kernel<<<1, 64, 0, stream>>>(idx_flat, vals, dst, wgt, cnt);
    scatter_kernel<<<NK / 2, 256, 0, stream>>>(x, dst, idx_flat, ex);

    // K2: gate+up GEMMs (expert + shared) + down-weight conversion
    GSeg segGE = {ex, (long)RPAD * DIM, RPAD, wgC, wuC, (long)DIM * FDIM,
                  acte, (long)RPAD * FDIM, RPAD, cnt, 3, 11, FDIM, DIM, 3 * 11 * NEXP};
    GSeg segGS = {xb, 0L, TOKENS, swgC, swuC, 0L,
                  acts, 0L, TOKENS, nullptr, 16, 11, FDIM, DIM, 16 * 11};
    gateup_kernel<<<segGE.nblocks + segGS.nblocks + Wd.nblocks + Wsd.nblocks,
                    256, 0, stream>>>(segGE, segGS, Wd, Wsd);

    // K3: down GEMMs (expert + shared)
    GSeg segDE = {acte, (long)RPAD * FDIM, RPAD, wdC, nullptr, (long)DIM * FDIM,
                  eout, (long)RPAD * DIM, 0, cnt, 3, 8, DIM, FDIM, 3 * 8 * NEXP};
    GSeg segDS = {acts, 0L, TOKENS, swdC, nullptr, 0L,
                  shout, 0L, 0, nullptr, 16, 8, DIM, FDIM, 16 * 8};
    down_kernel<<<segDE.nblocks + segDS.nblocks, 256, 0, stream>>>(segDE, segDS);

    combine_kernel<<<TOKENS, 256, 0, stream>>>(x, shout, eout, dst, wgt, out);
}

// Round 5
// 250.514 us; speedup vs baseline: 1.8258x; 1.8258x over previous
//
#include <hip/hip_runtime.h>
#include <hip/hip_bf16.h>

#define TOKENS 2048
#define DIM    1024
#define FDIM   1408
#define NEXP   16
#define NK     (TOKENS * 2)
#define CAP    320
#define RPAD   384          // padded rows per expert (3 x 128)

typedef __attribute__((ext_vector_type(4))) float f32x4;
typedef __attribute__((ext_vector_type(8))) short s16x8;
typedef __attribute__((ext_vector_type(4))) short s16x4;

__device__ __forceinline__ short f2bf(float f) {
    unsigned int u = __float_as_uint(f);
    u += 0x7FFFu + ((u >> 16) & 1u);   // RNE
    return (short)(u >> 16);
}
__device__ __forceinline__ float bf2f(short s) {
    return __uint_as_float(((unsigned int)(unsigned short)s) << 16);
}

#define GLDS16(gp, lp) __builtin_amdgcn_global_load_lds(                     \
    (const __attribute__((address_space(1))) unsigned int*)(gp),             \
    (__attribute__((address_space(3))) unsigned int*)(lp), 16, 0, 0)

// ---------------- arg structs ----------------
struct GSeg {
    const short* A; long aStride; int aRpad;
    const short* B0; const short* B1; long bStride;
    short* Out; long oStride; int oRpad;
    const int* cnt; int Mb, Nb, N, K, nblocks;
};
struct WSeg { const float* in; short* out; int K, N, mats, nblocks; };

// ------- Weight chunk-reorder device: fp32 [K][N] -> bf16 [K/8][N][8] -------
// block = 128 n-cols x 16 k-slabs; 256 threads, 8 units each
__device__ void wchunk_dev(const WSeg& W, int bid)
{
    const int pm  = W.nblocks / W.mats;
    const int mat = bid / pm, r = bid % pm;
    const int nbl = W.N >> 7;
    const int nb  = r % nbl, kb = r / nbl;
    const int t   = threadIdx.x;
    const int n   = nb * 128 + (t & 127);
    const int s0  = kb * 16 + (t >> 7);
    const float* in = W.in + (size_t)mat * W.K * W.N;
    short* out = W.out + (size_t)mat * W.K * W.N;
#pragma unroll
    for (int i = 0; i < 8; i++) {
        int s = s0 + i * 2;
        const float* src = in + (size_t)s * 8 * W.N + n;
        s16x8 o;
#pragma unroll
        for (int j = 0; j < 8; j++) o[j] = f2bf(src[(size_t)j * W.N]);
        *(s16x8*)(out + (size_t)s * W.N * 8 + (size_t)n * 8) = o;
    }
}

// -------- Router device: logits -> softmax -> top2 -> renormalize -----------
__device__ void router_dev(const float* __restrict__ x, const float* __restrict__ rw,
                           const float* __restrict__ rb, int* __restrict__ idx_flat,
                           float* __restrict__ vals_flat, int bid)
{
    __shared__ float lg[16][17];
    const int t  = threadIdx.x;
    const int tl = t >> 4;
    const int e  = t & 15;
    const int token = bid * 16 + tl;
    const float* xr = x + (size_t)token * DIM;

    float acc = 0.f;
    for (int d4 = 0; d4 < DIM / 4; d4++) {
        float4 xv = *(const float4*)(xr + d4 * 4);
        acc += xv.x * rw[(d4 * 4 + 0) * NEXP + e];
        acc += xv.y * rw[(d4 * 4 + 1) * NEXP + e];
        acc += xv.z * rw[(d4 * 4 + 2) * NEXP + e];
        acc += xv.w * rw[(d4 * 4 + 3) * NEXP + e];
    }
    lg[tl][e] = acc + rb[e];
    __syncthreads();

    if (t < 16) {
        float l[16];
#pragma unroll
        for (int j = 0; j < 16; j++) l[j] = lg[t][j];
        float m = l[0];
#pragma unroll
        for (int j = 1; j < 16; j++) m = fmaxf(m, l[j]);
        float p[16], den = 0.f;
#pragma unroll
        for (int j = 0; j < 16; j++) { p[j] = __expf(l[j] - m); den += p[j]; }
        int i1 = -1; float b1 = -1e30f;
#pragma unroll
        for (int j = 0; j < 16; j++) if (p[j] > b1) { b1 = p[j]; i1 = j; }
        int i2 = -1; float b2 = -1e30f;
#pragma unroll
        for (int j = 0; j < 16; j++) if (j != i1 && p[j] > b2) { b2 = p[j]; i2 = j; }
        float v1 = b1 / den, v2 = b2 / den;
        float s = v1 + v2 + 1e-9f;
        int tok = bid * 16 + t;
        idx_flat[tok * 2 + 0] = i1;
        idx_flat[tok * 2 + 1] = i2;
        vals_flat[tok * 2 + 0] = v1 / s;
        vals_flat[tok * 2 + 1] = v2 / s;
    }
}

// -------- xconv device: x -> bf16 chunk [DIM/8][TOKENS][8]; 2 tokens/block --
__device__ void xconv_dev(const float* __restrict__ x, short* __restrict__ xb, int bid)
{
    const int token = bid * 2 + (threadIdx.x >> 7);
    const int c = threadIdx.x & 127;
    const float* src = x + (size_t)token * DIM + c * 8;
    float4 v0 = *(const float4*)(src);
    float4 v1 = *(const float4*)(src + 4);
    s16x8 o;
    o[0] = f2bf(v0.x); o[1] = f2bf(v0.y); o[2] = f2bf(v0.z); o[3] = f2bf(v0.w);
    o[4] = f2bf(v1.x); o[5] = f2bf(v1.y); o[6] = f2bf(v1.z); o[7] = f2bf(v1.w);
    *(s16x8*)(xb + (size_t)c * (TOKENS * 8) + (size_t)token * 8) = o;
}

// ---------------- K1: weight(g/u) conversion + router + xconv ---------------
__global__ __launch_bounds__(256) void prep_kernel(
    WSeg w0, WSeg w1, WSeg w2, WSeg w3,
    const float* __restrict__ x, const float* __restrict__ rw,
    const float* __restrict__ rb, int* __restrict__ idx_flat,
    float* __restrict__ vals, short* __restrict__ xb)
{
    int bid = blockIdx.x;
    if (bid < w0.nblocks) { wchunk_dev(w0, bid); return; }
    bid -= w0.nblocks;
    if (bid < w1.nblocks) { wchunk_dev(w1, bid); return; }
    bid -= w1.nblocks;
    if (bid < w2.nblocks) { wchunk_dev(w2, bid); return; }
    bid -= w2.nblocks;
    if (bid < w3.nblocks) { wchunk_dev(w3, bid); return; }
    bid -= w3.nblocks;
    if (bid < TOKENS / 16) { router_dev(x, rw, rb, idx_flat, vals, bid); return; }
    bid -= TOKENS / 16;
    xconv_dev(x, xb, bid);
}

// ------------- Sequential position scan (1 wave, ballot-based) --------------
__global__ void scan_kernel(const int* __restrict__ idx_flat,
                            const float* __restrict__ vals,
                            int* __restrict__ dst, float* __restrict__ wgt,
                            int* __restrict__ cnt)
{
    const int lane = threadIdx.x;   // 64 threads
    int base[16];
#pragma unroll
    for (int e = 0; e < 16; e++) base[e] = 0;

    for (int c = 0; c < NK / 64; c++) {
        int i = c * 64 + lane;
        int e = idx_flat[i];
        unsigned long long m[16];
#pragma unroll
        for (int ee = 0; ee < 16; ee++) m[ee] = __ballot(e == ee);
        unsigned long long mym = 0ULL; int myb = 0;
#pragma unroll
        for (int ee = 0; ee < 16; ee++) {
            bool sel = (e == ee);
            mym = sel ? m[ee] : mym;
            myb = sel ? base[ee] : myb;
        }
        int pos = myb + (int)__popcll(mym & ((1ULL << lane) - 1ULL));
        bool within = pos < CAP;
        dst[i] = within ? (e * RPAD + pos) : -1;
        wgt[i] = within ? vals[i] : 0.f;
#pragma unroll
        for (int ee = 0; ee < 16; ee++) base[ee] += (int)__popcll(m[ee]);
    }
    if (lane < 16) cnt[lane] = base[lane] < CAP ? base[lane] : CAP;
}

// ---- Scatter token into expert buffer, chunk layout [K/8][RPAD][8] ---------
// 2 entries per block (256 threads)
__global__ __launch_bounds__(256) void scatter_kernel(
    const float* __restrict__ x, const int* __restrict__ dst,
    const int* __restrict__ idx_flat, short* __restrict__ ex)
{
    const int i = blockIdx.x * 2 + (threadIdx.x >> 7);
    const int d0 = dst[i];
    if (d0 < 0) return;
    const int e = idx_flat[i];
    const int pos = d0 - e * RPAD;
    const int token = i >> 1;
    const int c = threadIdx.x & 127;
    const float* src = x + (size_t)token * DIM + c * 8;
    float4 v0 = *(const float4*)(src);
    float4 v1 = *(const float4*)(src + 4);
    s16x8 o;
    o[0] = f2bf(v0.x); o[1] = f2bf(v0.y); o[2] = f2bf(v0.z); o[3] = f2bf(v0.w);
    o[4] = f2bf(v1.x); o[5] = f2bf(v1.y); o[6] = f2bf(v1.z); o[7] = f2bf(v1.w);
    *(s16x8*)(ex + (size_t)e * (DIM * RPAD) + (size_t)c * (RPAD * 8) +
              (size_t)pos * 8) = o;
}

// ---------------- Grouped GEMM device, depth-2 counted-vmcnt pipeline -------
// A: chunk [K/8][aRpad][8] bf16; B: chunk [K/8][N][8] bf16.
// NMAT=2: Out = silu(A@B0)*(A@B1) stored chunk [N/8][oRpad][8]
// NMAT=1: Out = A@B0 stored canonical [row][N]
// Tile 128x128(xNMAT), BK=32, 4 waves (2x2), each 64x64 per mat.
template <int NMAT>
__device__ void gemm_dev(const GSeg& S, int bid)
{
    constexpr int BUFS = 4096 * (1 + NMAT);     // shorts per pipeline buffer
    __shared__ short lds[2 * BUFS];

    // XCD-aware swizzle (segment nblocks % 8 == 0), m fastest
    const int cpx = S.nblocks >> 3;
    const int lid = (bid & 7) * cpx + (bid >> 3);
    const int mb  = lid % S.Mb;
    const int t1  = lid / S.Mb;
    const int nb  = t1 % S.Nb;
    const int g   = t1 / S.Nb;
    const int m0 = mb * 128, n0 = nb * 128;
    if (S.cnt != nullptr && m0 >= S.cnt[g]) return;

    const int tid = threadIdx.x, lane = tid & 63, w = tid >> 6;
    const int wr = w >> 1, wc = w & 1, ln = lane & 15, kg = lane >> 4;

    const int N = S.N, K = S.K;
    const short* Ag  = S.A  + (size_t)g * S.aStride + (size_t)m0 * 8;
    const short* Bg0 = S.B0 + (size_t)g * S.bStride + (size_t)n0 * 8;
    const short* Bg1 = nullptr;
    if constexpr (NMAT == 2) Bg1 = S.B1 + (size_t)g * S.bStride + (size_t)n0 * 8;

    const size_t aR8 = (size_t)S.aRpad * 8;   // shorts per A k-slab
    const size_t n8  = (size_t)N * 8;         // shorts per B k-slab

    const int srow = tid & 127, sslab = tid >> 7;
    const short* aS0 = Ag  + sslab * aR8 + srow * 8;
    const short* aS1 = Ag  + (2 + sslab) * aR8 + srow * 8;
    const short* bS00 = Bg0 + sslab * n8 + srow * 8;
    const short* bS01 = Bg0 + (2 + sslab) * n8 + srow * 8;
    const short* bS10 = nullptr, *bS11 = nullptr;
    if constexpr (NMAT == 2) {
        bS10 = Bg1 + sslab * n8 + srow * 8;
        bS11 = Bg1 + (2 + sslab) * n8 + srow * 8;
    }

    // wave-uniform LDS dest offsets (shorts): HW adds lane*16B
    const int dA0 = w * 512, dA1 = 2048 + w * 512;

    auto STG = [&](int buf, int ks) {
        const size_t ka = (size_t)ks * 4 * aR8;
        const size_t kb = (size_t)ks * 4 * n8;
        short* base = lds + buf * BUFS;
        GLDS16(aS0 + ka,  base + dA0);
        GLDS16(aS1 + ka,  base + dA1);
        GLDS16(bS00 + kb, base + 4096 + dA0);
        GLDS16(bS01 + kb, base + 4096 + dA1);
        if constexpr (NMAT == 2) {
            GLDS16(bS10 + kb, base + 8192 + dA0);
            GLDS16(bS11 + kb, base + 8192 + dA1);
        }
    };

    // frag read offsets (shorts): LDS per buf = [4 kg][128 row][8]
    const int aO = kg * 1024 + (wr * 64 + ln) * 8;
    const int bO = kg * 1024 + (wc * 64 + ln) * 8;

    f32x4 acc[NMAT][4][4] = {};

    const int nt = K / 32;
    STG(0, 0); STG(1, 1);
    int cur = 0;
    for (int ks = 0; ks < nt; ks++) {
        if (ks + 1 < nt) {
            if constexpr (NMAT == 2) asm volatile("s_waitcnt vmcnt(6)" ::: "memory");
            else                     asm volatile("s_waitcnt vmcnt(4)" ::: "memory");
        } else {
            asm volatile("s_waitcnt vmcnt(0)" ::: "memory");
        }
        __builtin_amdgcn_s_barrier();
        __builtin_amdgcn_sched_barrier(0);

        const short* base = lds + cur * BUFS;
        s16x8 af[4];
#pragma unroll
        for (int m = 0; m < 4; m++)
            af[m] = *(const s16x8*)(base + aO + m * 128);
        s16x8 bf[NMAT][4];
#pragma unroll
        for (int mat = 0; mat < NMAT; mat++)
#pragma unroll
            for (int nf = 0; nf < 4; nf++)
                bf[mat][nf] = *(const s16x8*)(base + 4096 + mat * 4096 + bO + nf * 128);

        __builtin_amdgcn_s_setprio(1);
#pragma unroll
        for (int nf = 0; nf < 4; nf++)
#pragma unroll
            for (int m = 0; m < 4; m++)
#pragma unroll
                for (int mat = 0; mat < NMAT; mat++)
                    acc[mat][m][nf] = __builtin_amdgcn_mfma_f32_16x16x32_bf16(
                        af[m], bf[mat][nf], acc[mat][m][nf], 0, 0, 0);
        __builtin_amdgcn_s_setprio(0);
        __builtin_amdgcn_sched_barrier(0);
        __builtin_amdgcn_s_barrier();

        if (ks + 2 < nt) STG(cur, ks + 2);
        cur ^= 1;
    }

    // Epilogue. C/D: col = lane&15, row = (lane>>4)*4 + j  [m89-verified]
#pragma unroll
    for (int m = 0; m < 4; m++) {
#pragma unroll
        for (int nf = 0; nf < 4; nf++) {
            const int row = m0 + wr * 64 + m * 16 + kg * 4;
            const int col = n0 + wc * 64 + nf * 16 + ln;
#pragma unroll
            for (int j = 0; j < 4; j++) {
                if constexpr (NMAT == 2) {
                    float gv = acc[0][m][nf][j];
                    float uv = acc[1][m][nf][j];
                    float v = gv / (1.f + __expf(-gv)) * uv;
                    S.Out[(size_t)g * S.oStride + (size_t)(col >> 3) * (S.oRpad * 8) +
                          (size_t)(row + j) * 8 + (col & 7)] = f2bf(v);
                } else {
                    S.Out[(size_t)g * S.oStride + (size_t)(row + j) * N + col] =
                        f2bf(acc[0][m][nf][j]);
                }
            }
        }
    }
}

// ---------------- K2: gate+up GEMMs + down-weight conversion ----------------
// NOTE: min-waves MUST stay at 2 (256 regs/thread). 3+ clamps the register
// budget below the 128 accumulator regs -> scratch spill -> 8x write traffic
// (measured round 4: WRITE_SIZE 575 MB vs 75 MB ideal, 285 us dispatch).
__global__ __launch_bounds__(256, 2) void gateup_kernel(GSeg s0, GSeg s1,
                                                        WSeg w0, WSeg w1)
{
    int bid = blockIdx.x;
    if (bid < s0.nblocks) { gemm_dev<2>(s0, bid); return; }
    bid -= s0.nblocks;
    if (bid < s1.nblocks) { gemm_dev<2>(s1, bid); return; }
    bid -= s1.nblocks;
    if (bid < w0.nblocks) { wchunk_dev(w0, bid); return; }
    bid -= w0.nblocks;
    wchunk_dev(w1, bid);
}

// ---------------- K3: down GEMMs --------------------------------------------
__global__ __launch_bounds__(256, 2) void down_kernel(GSeg s0, GSeg s1)
{
    int bid = blockIdx.x;
    if (bid < s0.nblocks) { gemm_dev<1>(s0, bid); return; }
    bid -= s0.nblocks;
    gemm_dev<1>(s1, bid);
}

// ---------------- Combine: out = x + shared + sum_k w_k * expert_row --------
__global__ __launch_bounds__(256) void combine_kernel(
    const float* __restrict__ x, const short* __restrict__ shout,
    const short* __restrict__ eout, const int* __restrict__ dst,
    const float* __restrict__ wgt, float* __restrict__ out)
{
    const int t = blockIdx.x;
    const int d = threadIdx.x * 4;
    size_t o = (size_t)t * DIM + d;
    float4 xv = *(const float4*)(x + o);
    s16x4 sv = *(const s16x4*)(shout + o);
    float r0 = xv.x + bf2f(sv[0]);
    float r1 = xv.y + bf2f(sv[1]);
    float r2 = xv.z + bf2f(sv[2]);
    float r3 = xv.w + bf2f(sv[3]);
#pragma unroll
    for (int k = 0; k < 2; k++) {
        int di = dst[t * 2 + k];
        if (di >= 0) {
            float wv = wgt[t * 2 + k];
            s16x4 ev = *(const s16x4*)(eout + (size_t)di * DIM + d);
            r0 += wv * bf2f(ev[0]);
            r1 += wv * bf2f(ev[1]);
            r2 += wv * bf2f(ev[2]);
            r3 += wv * bf2f(ev[3]);
        }
    }
    float4 rv = {r0, r1, r2, r3};
    *(float4*)(out + o) = rv;
}

extern "C" void kernel_launch(void* const* d_in, const int* in_sizes, int n_in,
                              void* d_out, int out_size, void* d_ws, size_t ws_size,
                              hipStream_t stream)
{
    const float* x   = (const float*)d_in[0];
    const float* rw  = (const float*)d_in[1];
    const float* rb  = (const float*)d_in[2];
    const float* wg  = (const float*)d_in[3];
    const float* wu  = (const float*)d_in[4];
    const float* wd  = (const float*)d_in[5];
    const float* swg = (const float*)d_in[6];
    const float* swu = (const float*)d_in[7];
    const float* swd = (const float*)d_in[8];
    float* out = (float*)d_out;

    char* wp = (char*)d_ws;
    auto alloc = [&](size_t b) { char* p = wp; wp += (b + 255) & ~(size_t)255; return p; };
    int*   idx_flat = (int*)alloc((size_t)NK * 4);
    float* vals     = (float*)alloc((size_t)NK * 4);
    int*   dst      = (int*)alloc((size_t)NK * 4);
    float* wgt      = (float*)alloc((size_t)NK * 4);
    int*   cnt      = (int*)alloc(64);
    short* xb       = (short*)alloc((size_t)TOKENS * DIM * 2);          // chunk
    short* ex       = (short*)alloc((size_t)NEXP * RPAD * DIM * 2);     // chunk
    short* acte     = (short*)alloc((size_t)NEXP * RPAD * FDIM * 2);    // chunk
    short* acts     = (short*)alloc((size_t)TOKENS * FDIM * 2);         // chunk
    short* eout     = (short*)alloc((size_t)NEXP * RPAD * DIM * 2);     // canonical
    short* shout    = (short*)alloc((size_t)TOKENS * DIM * 2);          // canonical
    short* wgC      = (short*)alloc((size_t)NEXP * DIM * FDIM * 2);
    short* wuC      = (short*)alloc((size_t)NEXP * DIM * FDIM * 2);
    short* wdC      = (short*)alloc((size_t)NEXP * DIM * FDIM * 2);
    short* swgC     = (short*)alloc((size_t)DIM * FDIM * 2);
    short* swuC     = (short*)alloc((size_t)DIM * FDIM * 2);
    short* swdC     = (short*)alloc((size_t)DIM * FDIM * 2);

    // WSeg: blocks/mat = (N/128)*(K/128)
    WSeg Wg  = {wg,  wgC,  DIM,  FDIM, NEXP, 11 * 8 * NEXP};   // 1408
    WSeg Wu  = {wu,  wuC,  DIM,  FDIM, NEXP, 11 * 8 * NEXP};   // 1408
    WSeg Wsg = {swg, swgC, DIM,  FDIM, 1,    11 * 8};          // 88
    WSeg Wsu = {swu, swuC, DIM,  FDIM, 1,    11 * 8};          // 88
    WSeg Wd  = {wd,  wdC,  FDIM, DIM,  NEXP, 8 * 11 * NEXP};   // 1408
    WSeg Wsd = {swd, swdC, FDIM, DIM,  1,    8 * 11};          // 88

    // K1: g/u weight conversion + router + xconv
    const int prep_blocks = Wg.nblocks + Wu.nblocks + Wsg.nblocks + Wsu.nblocks
                          + TOKENS / 16 + TOKENS / 2;
    prep_kernel<<<prep_blocks, 256, 0, stream>>>(Wg, Wu, Wsg, Wsu,
                                                 x, rw, rb, idx_flat, vals, xb);
    scan_kernel<<<1, 64, 0, stream>>>(idx_flat, vals, dst, wgt, cnt);
    scatter_kernel<<<NK / 2, 256, 0, stream>>>(x, dst, idx_flat, ex);

    // K2: gate+up GEMMs (expert + shared) + down-weight conversion
    GSeg segGE = {ex, (long)RPAD * DIM, RPAD, wgC, wuC, (long)DIM * FDIM,
                  acte, (long)RPAD * FDIM, RPAD, cnt, 3, 11, FDIM, DIM, 3 * 11 * NEXP};
    GSeg segGS = {xb, 0L, TOKENS, swgC, swuC, 0L,
                  acts, 0L, TOKENS, nullptr, 16, 11, FDIM, DIM, 16 * 11};
    gateup_kernel<<<segGE.nblocks + segGS.nblocks + Wd.nblocks + Wsd.nblocks,
                    256, 0, stream>>>(segGE, segGS, Wd, Wsd);

    // K3: down GEMMs (expert + shared)
    GSeg segDE = {acte, (long)RPAD * FDIM, RPAD, wdC, nullptr, (long)DIM * FDIM,
                  eout, (long)RPAD * DIM, 0, cnt, 3, 8, DIM, FDIM, 3 * 8 * NEXP};
    GSeg segDS = {acts, 0L, TOKENS, swdC, nullptr, 0L,
                  shout, 0L, 0, nullptr, 16, 8, DIM, FDIM, 16 * 8};
    down_kernel<<<segDE.nblocks + segDS.nblocks, 256, 0, stream>>>(segDE, segDS);

    combine_kernel<<<TOKENS, 256, 0, stream>>>(x, shout, eout, dst, wgt, out);
}

// Round 6
// 249.483 us; speedup vs baseline: 1.8333x; 1.0041x over previous
//
#include <hip/hip_runtime.h>
#include <hip/hip_bf16.h>

#define TOKENS 2048
#define DIM    1024
#define FDIM   1408
#define NEXP   16
#define NK     (TOKENS * 2)
#define CAP    320
#define RPAD   384          // padded rows per expert (3 x 128)

typedef __attribute__((ext_vector_type(4))) float f32x4;
typedef __attribute__((ext_vector_type(8))) short s16x8;
typedef __attribute__((ext_vector_type(4))) short s16x4;

__device__ __forceinline__ short f2bf(float f) {
    unsigned int u = __float_as_uint(f);
    u += 0x7FFFu + ((u >> 16) & 1u);   // RNE
    return (short)(u >> 16);
}
__device__ __forceinline__ float bf2f(short s) {
    return __uint_as_float(((unsigned int)(unsigned short)s) << 16);
}

#define GLDS16(gp, lp) __builtin_amdgcn_global_load_lds(                     \
    (const __attribute__((address_space(1))) unsigned int*)(gp),             \
    (__attribute__((address_space(3))) unsigned int*)(lp), 16, 0, 0)

// ---------------- arg structs ----------------
struct GSeg {
    const short* A; long aStride; int aRpad;
    const short* B0; const short* B1; long bStride;
    short* Out; long oStride; int oRpad;
    const int* cnt; int Mb, Nb, N, K, nblocks;
};
struct WSeg { const float* in; short* out; int K, N, mats, nblocks; };

// ------- Weight chunk-reorder: fp32 [K][N] -> bf16 [K/8][N][8] --------------
// Slab scheme: block = one 8-row k-slab; thread owns 2 adjacent cols for all
// 8 rows (float2). Reads 2 KB contiguous per row per iter; writes 8 KB
// contiguous per iter (slab output is linear in chunk layout).
// nblocks = mats * K/8.
__device__ void wchunk_dev(const WSeg& W, int bid)
{
    const int spm = W.K >> 3;            // slabs per matrix
    const int mat = bid / spm, s = bid % spm;
    const float* in  = W.in  + (size_t)mat * W.K * W.N + (size_t)s * 8 * W.N;
    short* out = W.out + (size_t)mat * W.K * W.N + (size_t)s * W.N * 8;
    const int t = threadIdx.x;
    const int iters = (W.N + 511) >> 9;
    for (int it = 0; it < iters; it++) {
        const int n = it * 512 + 2 * t;
        if (n >= W.N) break;
        const float* src = in + n;
        s16x8 o0, o1;
#pragma unroll
        for (int j = 0; j < 8; j++) {
            float2 v = *(const float2*)(src + (size_t)j * W.N);
            o0[j] = f2bf(v.x);
            o1[j] = f2bf(v.y);
        }
        *(s16x8*)(out + (size_t)n * 8)     = o0;
        *(s16x8*)(out + (size_t)n * 8 + 8) = o1;
    }
}

// ---------------- Router: logits -> softmax -> top2 -> renormalize ----------
__global__ __launch_bounds__(256) void router_kernel(
    const float* __restrict__ x, const float* __restrict__ rw,
    const float* __restrict__ rb, int* __restrict__ idx_flat,
    float* __restrict__ vals_flat)
{
    __shared__ float lg[16][17];
    const int t  = threadIdx.x;
    const int tl = t >> 4;
    const int e  = t & 15;
    const int token = blockIdx.x * 16 + tl;
    const float* xr = x + (size_t)token * DIM;

    float acc = 0.f;
    for (int d4 = 0; d4 < DIM / 4; d4++) {
        float4 xv = *(const float4*)(xr + d4 * 4);
        acc += xv.x * rw[(d4 * 4 + 0) * NEXP + e];
        acc += xv.y * rw[(d4 * 4 + 1) * NEXP + e];
        acc += xv.z * rw[(d4 * 4 + 2) * NEXP + e];
        acc += xv.w * rw[(d4 * 4 + 3) * NEXP + e];
    }
    lg[tl][e] = acc + rb[e];
    __syncthreads();

    if (t < 16) {
        float l[16];
#pragma unroll
        for (int j = 0; j < 16; j++) l[j] = lg[t][j];
        float m = l[0];
#pragma unroll
        for (int j = 1; j < 16; j++) m = fmaxf(m, l[j]);
        float p[16], den = 0.f;
#pragma unroll
        for (int j = 0; j < 16; j++) { p[j] = __expf(l[j] - m); den += p[j]; }
        int i1 = -1; float b1 = -1e30f;
#pragma unroll
        for (int j = 0; j < 16; j++) if (p[j] > b1) { b1 = p[j]; i1 = j; }
        int i2 = -1; float b2 = -1e30f;
#pragma unroll
        for (int j = 0; j < 16; j++) if (j != i1 && p[j] > b2) { b2 = p[j]; i2 = j; }
        float v1 = b1 / den, v2 = b2 / den;
        float s = v1 + v2 + 1e-9f;
        int tok = blockIdx.x * 16 + t;
        idx_flat[tok * 2 + 0] = i1;
        idx_flat[tok * 2 + 1] = i2;
        vals_flat[tok * 2 + 0] = v1 / s;
        vals_flat[tok * 2 + 1] = v2 / s;
    }
}

// ------------- Sequential position scan (1 wave, ballot-based) --------------
__global__ void scan_kernel(const int* __restrict__ idx_flat,
                            const float* __restrict__ vals,
                            int* __restrict__ dst, float* __restrict__ wgt,
                            int* __restrict__ cnt)
{
    const int lane = threadIdx.x;   // 64 threads
    int base[16];
#pragma unroll
    for (int e = 0; e < 16; e++) base[e] = 0;

    for (int c = 0; c < NK / 64; c++) {
        int i = c * 64 + lane;
        int e = idx_flat[i];
        unsigned long long m[16];
#pragma unroll
        for (int ee = 0; ee < 16; ee++) m[ee] = __ballot(e == ee);
        unsigned long long mym = 0ULL; int myb = 0;
#pragma unroll
        for (int ee = 0; ee < 16; ee++) {
            bool sel = (e == ee);
            mym = sel ? m[ee] : mym;
            myb = sel ? base[ee] : myb;
        }
        int pos = myb + (int)__popcll(mym & ((1ULL << lane) - 1ULL));
        bool within = pos < CAP;
        dst[i] = within ? (e * RPAD + pos) : -1;
        wgt[i] = within ? vals[i] : 0.f;
#pragma unroll
        for (int ee = 0; ee < 16; ee++) base[ee] += (int)__popcll(m[ee]);
    }
    if (lane < 16) cnt[lane] = base[lane] < CAP ? base[lane] : CAP;
}

// -------- xconv device: x -> bf16 chunk [DIM/8][TOKENS][8]; 2 tokens/block --
__device__ void xconv_dev(const float* __restrict__ x, short* __restrict__ xb, int bid)
{
    const int token = bid * 2 + (threadIdx.x >> 7);
    const int c = threadIdx.x & 127;
    const float* src = x + (size_t)token * DIM + c * 8;
    float4 v0 = *(const float4*)(src);
    float4 v1 = *(const float4*)(src + 4);
    s16x8 o;
    o[0] = f2bf(v0.x); o[1] = f2bf(v0.y); o[2] = f2bf(v0.z); o[3] = f2bf(v0.w);
    o[4] = f2bf(v1.x); o[5] = f2bf(v1.y); o[6] = f2bf(v1.z); o[7] = f2bf(v1.w);
    *(s16x8*)(xb + (size_t)c * (TOKENS * 8) + (size_t)token * 8) = o;
}

// ---- Scatter device: token into expert buffer chunk [K/8][RPAD][8] ---------
__device__ void scatter_dev(const float* __restrict__ x, const int* __restrict__ dst,
                            const int* __restrict__ idx_flat, short* __restrict__ ex,
                            int bid)
{
    const int i = bid * 2 + (threadIdx.x >> 7);
    const int d0 = dst[i];
    if (d0 < 0) return;
    const int e = idx_flat[i];
    const int pos = d0 - e * RPAD;
    const int token = i >> 1;
    const int c = threadIdx.x & 127;
    const float* src = x + (size_t)token * DIM + c * 8;
    float4 v0 = *(const float4*)(src);
    float4 v1 = *(const float4*)(src + 4);
    s16x8 o;
    o[0] = f2bf(v0.x); o[1] = f2bf(v0.y); o[2] = f2bf(v0.z); o[3] = f2bf(v0.w);
    o[4] = f2bf(v1.x); o[5] = f2bf(v1.y); o[6] = f2bf(v1.z); o[7] = f2bf(v1.w);
    *(s16x8*)(ex + (size_t)e * (DIM * RPAD) + (size_t)c * (RPAD * 8) +
              (size_t)pos * 8) = o;
}

// ---- K-mid: g/u weight conversion + xconv + scatter (no LDS, full occ) -----
__global__ __launch_bounds__(256) void mid_kernel(
    WSeg w0, WSeg w1, WSeg w2, WSeg w3,
    const float* __restrict__ x, short* __restrict__ xb,
    const int* __restrict__ dst, const int* __restrict__ idx_flat,
    short* __restrict__ ex)
{
    int bid = blockIdx.x;
    if (bid < w0.nblocks) { wchunk_dev(w0, bid); return; }
    bid -= w0.nblocks;
    if (bid < w1.nblocks) { wchunk_dev(w1, bid); return; }
    bid -= w1.nblocks;
    if (bid < w2.nblocks) { wchunk_dev(w2, bid); return; }
    bid -= w2.nblocks;
    if (bid < w3.nblocks) { wchunk_dev(w3, bid); return; }
    bid -= w3.nblocks;
    if (bid < TOKENS / 2) { xconv_dev(x, xb, bid); return; }
    bid -= TOKENS / 2;
    scatter_dev(x, dst, idx_flat, ex, bid);
}

// ---------------- Grouped GEMM device, depth-2 counted-vmcnt pipeline -------
// A: chunk [K/8][aRpad][8] bf16; B: chunk [K/8][N][8] bf16.
// NMAT=2: Out = silu(A@B0)*(A@B1) stored chunk [N/8][oRpad][8]
// NMAT=1: Out = A@B0 stored canonical [row][N]
// Tile 128x128(xNMAT), BK=32, 4 waves (2x2), each 64x64 per mat.
template <int NMAT>
__device__ void gemm_dev(const GSeg& S, int bid)
{
    constexpr int BUFS = 4096 * (1 + NMAT);     // shorts per pipeline buffer
    __shared__ short lds[2 * BUFS];

    // XCD-aware swizzle (segment nblocks % 8 == 0), m fastest
    const int cpx = S.nblocks >> 3;
    const int lid = (bid & 7) * cpx + (bid >> 3);
    const int mb  = lid % S.Mb;
    const int t1  = lid / S.Mb;
    const int nb  = t1 % S.Nb;
    const int g   = t1 / S.Nb;
    const int m0 = mb * 128, n0 = nb * 128;
    if (S.cnt != nullptr && m0 >= S.cnt[g]) return;

    const int tid = threadIdx.x, lane = tid & 63, w = tid >> 6;
    const int wr = w >> 1, wc = w & 1, ln = lane & 15, kg = lane >> 4;

    const int N = S.N, K = S.K;
    const short* Ag  = S.A  + (size_t)g * S.aStride + (size_t)m0 * 8;
    const short* Bg0 = S.B0 + (size_t)g * S.bStride + (size_t)n0 * 8;
    const short* Bg1 = nullptr;
    if constexpr (NMAT == 2) Bg1 = S.B1 + (size_t)g * S.bStride + (size_t)n0 * 8;

    const size_t aR8 = (size_t)S.aRpad * 8;   // shorts per A k-slab
    const size_t n8  = (size_t)N * 8;         // shorts per B k-slab

    const int srow = tid & 127, sslab = tid >> 7;
    const short* aS0 = Ag  + sslab * aR8 + srow * 8;
    const short* aS1 = Ag  + (2 + sslab) * aR8 + srow * 8;
    const short* bS00 = Bg0 + sslab * n8 + srow * 8;
    const short* bS01 = Bg0 + (2 + sslab) * n8 + srow * 8;
    const short* bS10 = nullptr, *bS11 = nullptr;
    if constexpr (NMAT == 2) {
        bS10 = Bg1 + sslab * n8 + srow * 8;
        bS11 = Bg1 + (2 + sslab) * n8 + srow * 8;
    }

    // wave-uniform LDS dest offsets (shorts): HW adds lane*16B
    const int dA0 = w * 512, dA1 = 2048 + w * 512;

    auto STG = [&](int buf, int ks) {
        const size_t ka = (size_t)ks * 4 * aR8;
        const size_t kb = (size_t)ks * 4 * n8;
        short* base = lds + buf * BUFS;
        GLDS16(aS0 + ka,  base + dA0);
        GLDS16(aS1 + ka,  base + dA1);
        GLDS16(bS00 + kb, base + 4096 + dA0);
        GLDS16(bS01 + kb, base + 4096 + dA1);
        if constexpr (NMAT == 2) {
            GLDS16(bS10 + kb, base + 8192 + dA0);
            GLDS16(bS11 + kb, base + 8192 + dA1);
        }
    };

    // frag read offsets (shorts): LDS per buf = [4 kg][128 row][8]
    const int aO = kg * 1024 + (wr * 64 + ln) * 8;
    const int bO = kg * 1024 + (wc * 64 + ln) * 8;

    f32x4 acc[NMAT][4][4] = {};

    const int nt = K / 32;
    STG(0, 0); STG(1, 1);
    int cur = 0;
    for (int ks = 0; ks < nt; ks++) {
        if (ks + 1 < nt) {
            if constexpr (NMAT == 2) asm volatile("s_waitcnt vmcnt(6)" ::: "memory");
            else                     asm volatile("s_waitcnt vmcnt(4)" ::: "memory");
        } else {
            asm volatile("s_waitcnt vmcnt(0)" ::: "memory");
        }
        __builtin_amdgcn_s_barrier();
        __builtin_amdgcn_sched_barrier(0);

        const short* base = lds + cur * BUFS;
        s16x8 af[4];
#pragma unroll
        for (int m = 0; m < 4; m++)
            af[m] = *(const s16x8*)(base + aO + m * 128);
        s16x8 bf[NMAT][4];
#pragma unroll
        for (int mat = 0; mat < NMAT; mat++)
#pragma unroll
            for (int nf = 0; nf < 4; nf++)
                bf[mat][nf] = *(const s16x8*)(base + 4096 + mat * 4096 + bO + nf * 128);

        __builtin_amdgcn_s_setprio(1);
#pragma unroll
        for (int nf = 0; nf < 4; nf++)
#pragma unroll
            for (int m = 0; m < 4; m++)
#pragma unroll
                for (int mat = 0; mat < NMAT; mat++)
                    acc[mat][m][nf] = __builtin_amdgcn_mfma_f32_16x16x32_bf16(
                        af[m], bf[mat][nf], acc[mat][m][nf], 0, 0, 0);
        __builtin_amdgcn_s_setprio(0);
        __builtin_amdgcn_sched_barrier(0);
        __builtin_amdgcn_s_barrier();

        if (ks + 2 < nt) STG(cur, ks + 2);
        cur ^= 1;
    }

    // Epilogue. C/D: col = lane&15, row = (lane>>4)*4 + j  [m89-verified]
#pragma unroll
    for (int m = 0; m < 4; m++) {
#pragma unroll
        for (int nf = 0; nf < 4; nf++) {
            const int row = m0 + wr * 64 + m * 16 + kg * 4;
            const int col = n0 + wc * 64 + nf * 16 + ln;
#pragma unroll
            for (int j = 0; j < 4; j++) {
                if constexpr (NMAT == 2) {
                    float gv = acc[0][m][nf][j];
                    float uv = acc[1][m][nf][j];
                    float v = gv / (1.f + __expf(-gv)) * uv;
                    S.Out[(size_t)g * S.oStride + (size_t)(col >> 3) * (S.oRpad * 8) +
                          (size_t)(row + j) * 8 + (col & 7)] = f2bf(v);
                } else {
                    S.Out[(size_t)g * S.oStride + (size_t)(row + j) * N + col] =
                        f2bf(acc[0][m][nf][j]);
                }
            }
        }
    }
}

// ---------------- K2: gate+up GEMMs + down-weight conversion ----------------
// NOTE: min-waves MUST stay at 2 (256 regs/thread). 3+ clamps the register
// budget below the 128 accumulator regs -> scratch spill -> 8x write traffic
// (measured round 4: WRITE_SIZE 575 MB vs 75 MB ideal, 285 us dispatch).
__global__ __launch_bounds__(256, 2) void gateup_kernel(GSeg s0, GSeg s1,
                                                        WSeg w0, WSeg w1)
{
    int bid = blockIdx.x;
    if (bid < s0.nblocks) { gemm_dev<2>(s0, bid); return; }
    bid -= s0.nblocks;
    if (bid < s1.nblocks) { gemm_dev<2>(s1, bid); return; }
    bid -= s1.nblocks;
    if (bid < w0.nblocks) { wchunk_dev(w0, bid); return; }
    bid -= w0.nblocks;
    wchunk_dev(w1, bid);
}

// ---------------- K3: down GEMMs --------------------------------------------
__global__ __launch_bounds__(256, 2) void down_kernel(GSeg s0, GSeg s1)
{
    int bid = blockIdx.x;
    if (bid < s0.nblocks) { gemm_dev<1>(s0, bid); return; }
    bid -= s0.nblocks;
    gemm_dev<1>(s1, bid);
}

// ---------------- Combine: out = x + shared + sum_k w_k * expert_row --------
__global__ __launch_bounds__(256) void combine_kernel(
    const float* __restrict__ x, const short* __restrict__ shout,
    const short* __restrict__ eout, const int* __restrict__ dst,
    const float* __restrict__ wgt, float* __restrict__ out)
{
    const int t = blockIdx.x;
    const int d = threadIdx.x * 4;
    size_t o = (size_t)t * DIM + d;
    float4 xv = *(const float4*)(x + o);
    s16x4 sv = *(const s16x4*)(shout + o);
    float r0 = xv.x + bf2f(sv[0]);
    float r1 = xv.y + bf2f(sv[1]);
    float r2 = xv.z + bf2f(sv[2]);
    float r3 = xv.w + bf2f(sv[3]);
#pragma unroll
    for (int k = 0; k < 2; k++) {
        int di = dst[t * 2 + k];
        if (di >= 0) {
            float wv = wgt[t * 2 + k];
            s16x4 ev = *(const s16x4*)(eout + (size_t)di * DIM + d);
            r0 += wv * bf2f(ev[0]);
            r1 += wv * bf2f(ev[1]);
            r2 += wv * bf2f(ev[2]);
            r3 += wv * bf2f(ev[3]);
        }
    }
    float4 rv = {r0, r1, r2, r3};
    *(float4*)(out + o) = rv;
}

extern "C" void kernel_launch(void* const* d_in, const int* in_sizes, int n_in,
                              void* d_out, int out_size, void* d_ws, size_t ws_size,
                              hipStream_t stream)
{
    const float* x   = (const float*)d_in[0];
    const float* rw  = (const float*)d_in[1];
    const float* rb  = (const float*)d_in[2];
    const float* wg  = (const float*)d_in[3];
    const float* wu  = (const float*)d_in[4];
    const float* wd  = (const float*)d_in[5];
    const float* swg = (const float*)d_in[6];
    const float* swu = (const float*)d_in[7];
    const float* swd = (const float*)d_in[8];
    float* out = (float*)d_out;

    char* wp = (char*)d_ws;
    auto alloc = [&](size_t b) { char* p = wp; wp += (b + 255) & ~(size_t)255; return p; };
    int*   idx_flat = (int*)alloc((size_t)NK * 4);
    float* vals     = (float*)alloc((size_t)NK * 4);
    int*   dst      = (int*)alloc((size_t)NK * 4);
    float* wgt      = (float*)alloc((size_t)NK * 4);
    int*   cnt      = (int*)alloc(64);
    short* xb       = (short*)alloc((size_t)TOKENS * DIM * 2);          // chunk
    short* ex       = (short*)alloc((size_t)NEXP * RPAD * DIM * 2);     // chunk
    short* acte     = (short*)alloc((size_t)NEXP * RPAD * FDIM * 2);    // chunk
    short* acts     = (short*)alloc((size_t)TOKENS * FDIM * 2);         // chunk
    short* eout     = (short*)alloc((size_t)NEXP * RPAD * DIM * 2);     // canonical
    short* shout    = (short*)alloc((size_t)TOKENS * DIM * 2);          // canonical
    short* wgC      = (short*)alloc((size_t)NEXP * DIM * FDIM * 2);
    short* wuC      = (short*)alloc((size_t)NEXP * DIM * FDIM * 2);
    short* wdC      = (short*)alloc((size_t)NEXP * DIM * FDIM * 2);
    short* swgC     = (short*)alloc((size_t)DIM * FDIM * 2);
    short* swuC     = (short*)alloc((size_t)DIM * FDIM * 2);
    short* swdC     = (short*)alloc((size_t)DIM * FDIM * 2);

    // WSeg: nblocks = mats * K/8 (one block per 8-row slab)
    WSeg Wg  = {wg,  wgC,  DIM,  FDIM, NEXP, NEXP * (DIM / 8)};    // 2048
    WSeg Wu  = {wu,  wuC,  DIM,  FDIM, NEXP, NEXP * (DIM / 8)};    // 2048
    WSeg Wsg = {swg, swgC, DIM,  FDIM, 1,    DIM / 8};             // 128
    WSeg Wsu = {swu, swuC, DIM,  FDIM, 1,    DIM / 8};             // 128
    WSeg Wd  = {wd,  wdC,  FDIM, DIM,  NEXP, NEXP * (FDIM / 8)};   // 2816
    WSeg Wsd = {swd, swdC, FDIM, DIM,  1,    FDIM / 8};            // 176

    // K1: router (critical path for scan)
    router_kernel<<<TOKENS / 16, 256, 0, stream>>>(x, rw, rb, idx_flat, vals);
    scan_kernel<<<1, 64, 0, stream>>>(idx_flat, vals, dst, wgt, cnt);

    // K-mid: g/u weight conversion + xconv + scatter (full occupancy)
    const int mid_blocks = Wg.nblocks + Wu.nblocks + Wsg.nblocks + Wsu.nblocks
                         + TOKENS / 2 + NK / 2;
    mid_kernel<<<mid_blocks, 256, 0, stream>>>(Wg, Wu, Wsg, Wsu,
                                               x, xb, dst, idx_flat, ex);

    // K2: gate+up GEMMs (expert + shared) + down-weight conversion
    GSeg segGE = {ex, (long)RPAD * DIM, RPAD, wgC, wuC, (long)DIM * FDIM,
                  acte, (long)RPAD * FDIM, RPAD, cnt, 3, 11, FDIM, DIM, 3 * 11 * NEXP};
    GSeg segGS = {xb, 0L, TOKENS, swgC, swuC, 0L,
                  acts, 0L, TOKENS, nullptr, 16, 11, FDIM, DIM, 16 * 11};
    gateup_kernel<<<segGE.nblocks + segGS.nblocks + Wd.nblocks + Wsd.nblocks,
                    256, 0, stream>>>(segGE, segGS, Wd, Wsd);

    // K3: down GEMMs (expert + shared)
    GSeg segDE = {acte, (long)RPAD * FDIM, RPAD, wdC, nullptr, (long)DIM * FDIM,
                  eout, (long)RPAD * DIM, 0, cnt, 3, 8, DIM, FDIM, 3 * 8 * NEXP};
    GSeg segDS = {acts, 0L, TOKENS, swdC, nullptr, 0L,
                  shout, 0L, 0, nullptr, 16, 8, DIM, FDIM, 16 * 8};
    down_kernel<<<segDE.nblocks + segDS.nblocks, 256, 0, stream>>>(segDE, segDS);

    combine_kernel<<<TOKENS, 256, 0, stream>>>(x, shout, eout, dst, wgt, out);
}